// Round 1
// baseline (910.096 us; speedup 1.0000x reference)
//
#include <hip/hip_runtime.h>
#include <hip/hip_bf16.h>

// ---------------------------------------------------------------------------
// 2-layer GCN, N=100000 nodes, E=3200000 edges, 128 -> 64 -> 64.
// out[i] = dinv[i] * sum_{e: dst=i} g[src_e] + b   with g = (x@W)*dinv,
// self-loop contributes g[i]. dinv = rsqrt(indeg+1).
// Pipeline: detect-dtype -> count -> scan -> CSR scatter -> gemm1 -> agg1(relu)
//           -> gemm2 -> agg2.
// ---------------------------------------------------------------------------

__global__ void k_init(int* cnt, int* cursor, int* flag, int n) {
    int i = blockIdx.x * blockDim.x + threadIdx.x;
    if (i < n) { cnt[i] = 0; cursor[i] = 0; }
    if (i == 0) *flag = 0;
}

// Decide whether edge_index is stored as int32 or int64.
// If int64 (values < 2^31), every odd 32-bit word (high half) is 0.
// If int32, odd words are random edge indices (P(all 1024 samples == 0) ~ 0).
__global__ void k_detect(const int* ei, int* flag, long long E) {
    int t = blockIdx.x * blockDim.x + threadIdx.x;   // 1024 threads
    long long k = (long long)t * (E / 1024);
    if (k < E) {
        if (ei[2 * k + 1] != 0) atomicOr(flag, 1);   // 1 => int32 layout
    }
}

__device__ __forceinline__ int edge_at(const int* ei, int is32, long long idx) {
    return is32 ? ei[idx] : ei[2 * idx];
}

__global__ void k_count(const int* ei, const int* flag, int* cnt, long long E) {
    long long e = (long long)blockIdx.x * blockDim.x + threadIdx.x;
    if (e >= E) return;
    int is32 = *flag;
    int d = edge_at(ei, is32, E + e);                // dst row
    atomicAdd(&cnt[d], 1);
}

// ---- 3-kernel exclusive scan over cnt[0..n) -> rowp, chunk = 256 ----
__global__ void k_scan1(const int* cnt, int* bsum, int n) {
    __shared__ int s[256];
    int t = threadIdx.x;
    int i = blockIdx.x * 256 + t;
    s[t] = (i < n) ? cnt[i] : 0;
    __syncthreads();
    for (int d = 128; d > 0; d >>= 1) {
        if (t < d) s[t] += s[t + d];
        __syncthreads();
    }
    if (t == 0) bsum[blockIdx.x] = s[0];
}

__global__ void k_scan2(const int* bsum, int* boff, int g) {
    __shared__ int s[512];
    int t = threadIdx.x;
    int v = (t < g) ? bsum[t] : 0;
    s[t] = v;
    __syncthreads();
    for (int d = 1; d < 512; d <<= 1) {
        int x = (t >= d) ? s[t - d] : 0;
        __syncthreads();
        s[t] += x;
        __syncthreads();
    }
    if (t < g) boff[t] = s[t] - v;                   // exclusive
}

__global__ void k_scan3(const int* cnt, const int* boff, int* rowp, int n) {
    __shared__ int s[256];
    int t = threadIdx.x;
    int i = blockIdx.x * 256 + t;
    int v = (i < n) ? cnt[i] : 0;
    s[t] = v;
    __syncthreads();
    for (int d = 1; d < 256; d <<= 1) {
        int x = (t >= d) ? s[t - d] : 0;
        __syncthreads();
        s[t] += x;
        __syncthreads();
    }
    if (i < n) rowp[i] = boff[blockIdx.x] + s[t] - v;
    if (i == n - 1) rowp[n] = boff[blockIdx.x] + s[t];
}

__global__ void k_dinv(const int* cnt, float* dinv, int n) {
    int i = blockIdx.x * blockDim.x + threadIdx.x;
    if (i < n) dinv[i] = rsqrtf((float)(cnt[i] + 1));  // +1 self loop
}

__global__ void k_scatter(const int* ei, const int* flag, const int* rowp,
                          int* cursor, int* esrc, long long E) {
    long long e = (long long)blockIdx.x * blockDim.x + threadIdx.x;
    if (e >= E) return;
    int is32 = *flag;
    int s = edge_at(ei, is32, e);
    int d = edge_at(ei, is32, E + e);
    int pos = atomicAdd(&cursor[d], 1);
    esrc[rowp[d] + pos] = s;
}

// g[r][lane] = (X[r] . W[:,lane]) * dinv[r]; wave per row, lane = out dim.
template <int K_IN>
__global__ __launch_bounds__(256) void k_gemm(const float* __restrict__ X,
                                              const float* __restrict__ W,
                                              const float* __restrict__ dinv,
                                              float* __restrict__ G, int n) {
    __shared__ float Wl[K_IN * 64];
    for (int i = threadIdx.x; i < K_IN * 64; i += blockDim.x) Wl[i] = W[i];
    __syncthreads();
    int lane = threadIdx.x & 63;
    int wid = blockIdx.x * (blockDim.x >> 6) + (threadIdx.x >> 6);
    int nw = gridDim.x * (blockDim.x >> 6);
    for (int r = wid; r < n; r += nw) {
        const float* xr = X + (size_t)r * K_IN;
        float acc = 0.f;
#pragma unroll
        for (int k = 0; k < K_IN; k += 4) {
            float4 xv = *(const float4*)(xr + k);      // wave-broadcast load
            acc = fmaf(xv.x, Wl[(k + 0) * 64 + lane], acc);
            acc = fmaf(xv.y, Wl[(k + 1) * 64 + lane], acc);
            acc = fmaf(xv.z, Wl[(k + 2) * 64 + lane], acc);
            acc = fmaf(xv.w, Wl[(k + 3) * 64 + lane], acc);
        }
        G[(size_t)r * 64 + lane] = acc * dinv[r];
    }
}

// wave per node: coalesced 256B gathers of g[src], register accumulate.
template <bool RELU>
__global__ __launch_bounds__(256) void k_agg(const float* __restrict__ G,
                                             const int* __restrict__ rowp,
                                             const int* __restrict__ esrc,
                                             const float* __restrict__ dinv,
                                             const float* __restrict__ bias,
                                             float* __restrict__ OUT, int n) {
    int lane = threadIdx.x & 63;
    int i = blockIdx.x * (blockDim.x >> 6) + (threadIdx.x >> 6);
    if (i >= n) return;
    float acc = G[(size_t)i * 64 + lane];              // self loop
    int e = rowp[i], e1 = rowp[i + 1];
    for (; e + 4 <= e1; e += 4) {
        int s0 = esrc[e], s1 = esrc[e + 1], s2 = esrc[e + 2], s3 = esrc[e + 3];
        float a0 = G[(size_t)s0 * 64 + lane];
        float a1 = G[(size_t)s1 * 64 + lane];
        float a2 = G[(size_t)s2 * 64 + lane];
        float a3 = G[(size_t)s3 * 64 + lane];
        acc += a0; acc += a1; acc += a2; acc += a3;
    }
    for (; e < e1; ++e) acc += G[(size_t)esrc[e] * 64 + lane];
    float r = dinv[i] * acc + bias[lane];
    if (RELU) r = fmaxf(r, 0.f);
    OUT[(size_t)i * 64 + lane] = r;
}

extern "C" void kernel_launch(void* const* d_in, const int* in_sizes, int n_in,
                              void* d_out, int out_size, void* d_ws, size_t ws_size,
                              hipStream_t stream) {
    const float* x = (const float*)d_in[0];
    const int* ei = (const int*)d_in[1];
    const float* W1 = (const float*)d_in[2];
    const float* b1 = (const float*)d_in[3];
    const float* W2 = (const float*)d_in[4];
    const float* b2 = (const float*)d_in[5];
    float* out = (float*)d_out;

    const int N = in_sizes[0] / 128;
    const long long E = in_sizes[1] / 2;
    const int G_SCAN = (N + 255) / 256;   // <= 512 for N <= 131072

    char* p = (char*)d_ws;
    size_t off = 0;
    auto take = [&](size_t bytes) -> void* {
        void* r = p + off;
        off += (bytes + 255) & ~(size_t)255;
        return r;
    };
    int* cnt = (int*)take((size_t)N * 4);
    int* cursor = (int*)take((size_t)N * 4);
    int* rowp = (int*)take((size_t)(N + 1) * 4);
    int* bsum = (int*)take(512 * 4);
    int* boff = (int*)take(512 * 4);
    int* flag = (int*)take(4);
    float* dinv = (float*)take((size_t)N * 4);
    int* esrc = (int*)take((size_t)E * 4);
    float* gbuf = (float*)take((size_t)N * 64 * 4);
    float* hbuf = (float*)take((size_t)N * 64 * 4);
    (void)ws_size; (void)n_in; (void)out_size;

    int nb_n = (N + 255) / 256;
    int nb_e = (int)((E + 255) / 256);

    k_init<<<nb_n, 256, 0, stream>>>(cnt, cursor, flag, N);
    k_detect<<<4, 256, 0, stream>>>(ei, flag, E);
    k_count<<<nb_e, 256, 0, stream>>>(ei, flag, cnt, E);
    k_scan1<<<G_SCAN, 256, 0, stream>>>(cnt, bsum, N);
    k_scan2<<<1, 512, 0, stream>>>(bsum, boff, G_SCAN);
    k_scan3<<<G_SCAN, 256, 0, stream>>>(cnt, boff, rowp, N);
    k_dinv<<<nb_n, 256, 0, stream>>>(cnt, dinv, N);
    k_scatter<<<nb_e, 256, 0, stream>>>(ei, flag, rowp, cursor, esrc, E);

    k_gemm<128><<<2048, 256, 0, stream>>>(x, W1, dinv, gbuf, N);
    k_agg<true><<<(N + 3) / 4, 256, 0, stream>>>(gbuf, rowp, esrc, dinv, b1, hbuf, N);
    k_gemm<64><<<2048, 256, 0, stream>>>(hbuf, W2, dinv, gbuf, N);
    k_agg<false><<<(N + 3) / 4, 256, 0, stream>>>(gbuf, rowp, esrc, dinv, b2, out, N);
}

// Round 2
// 638.541 us; speedup vs baseline: 1.4253x; 1.4253x over previous
//
#include <hip/hip_runtime.h>
#include <hip/hip_bf16.h>

// ---------------------------------------------------------------------------
// 2-layer GCN, N=100000 nodes, E=3200000 edges, 128 -> 64 -> 64.
// out[i] = dinv[i] * sum_{e: dst=i} g[src_e] + b   with g = (x@W)*dinv,
// self-loop contributes g[i]. dinv = rsqrt(indeg+1).
// Pipeline: detect-dtype -> count -> scan -> CSR scatter -> gemm1 -> agg1(relu)
//           -> gemm2 -> agg2.
// ---------------------------------------------------------------------------

__global__ void k_init(int* cnt, int* cursor, int* flag, int n) {
    int i = blockIdx.x * blockDim.x + threadIdx.x;
    if (i < n) { cnt[i] = 0; cursor[i] = 0; }
    if (i == 0) *flag = 0;
}

// Decide whether edge_index is stored as int32 or int64.
__global__ void k_detect(const int* ei, int* flag, long long E) {
    int t = blockIdx.x * blockDim.x + threadIdx.x;   // 1024 threads
    long long k = (long long)t * (E / 1024);
    if (k < E) {
        if (ei[2 * k + 1] != 0) atomicOr(flag, 1);   // 1 => int32 layout
    }
}

__device__ __forceinline__ int edge_at(const int* ei, int is32, long long idx) {
    return is32 ? ei[idx] : ei[2 * idx];
}

__global__ void k_count(const int* ei, const int* flag, int* cnt, long long E) {
    long long e = (long long)blockIdx.x * blockDim.x + threadIdx.x;
    if (e >= E) return;
    int is32 = *flag;
    int d = edge_at(ei, is32, E + e);                // dst row
    atomicAdd(&cnt[d], 1);
}

// ---- 3-kernel exclusive scan over cnt[0..n) -> rowp, chunk = 256 ----
__global__ void k_scan1(const int* cnt, int* bsum, int n) {
    __shared__ int s[256];
    int t = threadIdx.x;
    int i = blockIdx.x * 256 + t;
    s[t] = (i < n) ? cnt[i] : 0;
    __syncthreads();
    for (int d = 128; d > 0; d >>= 1) {
        if (t < d) s[t] += s[t + d];
        __syncthreads();
    }
    if (t == 0) bsum[blockIdx.x] = s[0];
}

__global__ void k_scan2(const int* bsum, int* boff, int g) {
    __shared__ int s[512];
    int t = threadIdx.x;
    int v = (t < g) ? bsum[t] : 0;
    s[t] = v;
    __syncthreads();
    for (int d = 1; d < 512; d <<= 1) {
        int x = (t >= d) ? s[t - d] : 0;
        __syncthreads();
        s[t] += x;
        __syncthreads();
    }
    if (t < g) boff[t] = s[t] - v;                   // exclusive
}

__global__ void k_scan3(const int* cnt, const int* boff, int* rowp, int n) {
    __shared__ int s[256];
    int t = threadIdx.x;
    int i = blockIdx.x * 256 + t;
    int v = (i < n) ? cnt[i] : 0;
    s[t] = v;
    __syncthreads();
    for (int d = 1; d < 256; d <<= 1) {
        int x = (t >= d) ? s[t - d] : 0;
        __syncthreads();
        s[t] += x;
        __syncthreads();
    }
    if (i < n) rowp[i] = boff[blockIdx.x] + s[t] - v;
    if (i == n - 1) rowp[n] = boff[blockIdx.x] + s[t];
}

__global__ void k_dinv(const int* cnt, float* dinv, int n) {
    int i = blockIdx.x * blockDim.x + threadIdx.x;
    if (i < n) dinv[i] = rsqrtf((float)(cnt[i] + 1));  // +1 self loop
}

__global__ void k_scatter(const int* ei, const int* flag, const int* rowp,
                          int* cursor, int* esrc, long long E) {
    long long e = (long long)blockIdx.x * blockDim.x + threadIdx.x;
    if (e >= E) return;
    int is32 = *flag;
    int s = edge_at(ei, is32, e);
    int d = edge_at(ei, is32, E + e);
    int pos = atomicAdd(&cursor[d], 1);
    esrc[rowp[d] + pos] = s;
}

// ---------------------------------------------------------------------------
// Register-tiled GEMM: C[n x 64] = X[n x K_IN] * W[K_IN x 64], scaled by dinv.
// Block = 256 threads, tile = 64 rows x 64 cols, thread = 4x4 micro-tile.
// BK=32 k-panel staged in LDS with coalesced float4 loads.
// Xs padded [64][33]: inner-loop reads Xs[r][k] (k uniform) hit 16 distinct
// banks, broadcast within tx-groups -> conflict-free. Ws unpadded for
// aligned ds_read_b128 of W[k][tx*4..tx*4+3].
// ---------------------------------------------------------------------------
template <int K_IN>
__global__ __launch_bounds__(256) void k_gemm2(const float* __restrict__ X,
                                               const float* __restrict__ W,
                                               const float* __restrict__ dinv,
                                               float* __restrict__ G, int n) {
    __shared__ float Xs[64][33];
    __shared__ float Ws[32][64];
    const int t = threadIdx.x;
    const int tx = t & 15;          // col quad: cols tx*4 .. tx*4+3
    const int ty = t >> 4;          // row quad: rows ty*4 .. ty*4+3
    const int r0 = blockIdx.x * 64;

    float acc[4][4] = {};

    for (int kb = 0; kb < K_IN; kb += 32) {
        // stage X panel: 64 rows x 32 k
        {
            const int kq = t & 7;       // k-quad within panel
            const int rr = t >> 3;      // 0..31
#pragma unroll
            for (int it = 0; it < 2; ++it) {
                int r = r0 + rr + it * 32;
                int rc = r < n ? r : n - 1;
                float4 xv = *(const float4*)(X + (size_t)rc * K_IN + kb + kq * 4);
                float* xd = &Xs[rr + it * 32][kq * 4];
                xd[0] = xv.x; xd[1] = xv.y; xd[2] = xv.z; xd[3] = xv.w;
            }
        }
        // stage W panel: 32 k x 64 cols
        {
            const int cq = t & 15;
            const int kr = t >> 4;      // 0..15
#pragma unroll
            for (int it = 0; it < 2; ++it) {
                float4 wv = *(const float4*)(W + (size_t)(kb + kr + it * 16) * 64 + cq * 4);
                *(float4*)&Ws[kr + it * 16][cq * 4] = wv;
            }
        }
        __syncthreads();
#pragma unroll 8
        for (int k = 0; k < 32; ++k) {
            float4 wv = *(const float4*)&Ws[k][tx * 4];
            float x0 = Xs[ty * 4 + 0][k];
            float x1 = Xs[ty * 4 + 1][k];
            float x2 = Xs[ty * 4 + 2][k];
            float x3 = Xs[ty * 4 + 3][k];
            acc[0][0] = fmaf(x0, wv.x, acc[0][0]);
            acc[0][1] = fmaf(x0, wv.y, acc[0][1]);
            acc[0][2] = fmaf(x0, wv.z, acc[0][2]);
            acc[0][3] = fmaf(x0, wv.w, acc[0][3]);
            acc[1][0] = fmaf(x1, wv.x, acc[1][0]);
            acc[1][1] = fmaf(x1, wv.y, acc[1][1]);
            acc[1][2] = fmaf(x1, wv.z, acc[1][2]);
            acc[1][3] = fmaf(x1, wv.w, acc[1][3]);
            acc[2][0] = fmaf(x2, wv.x, acc[2][0]);
            acc[2][1] = fmaf(x2, wv.y, acc[2][1]);
            acc[2][2] = fmaf(x2, wv.z, acc[2][2]);
            acc[2][3] = fmaf(x2, wv.w, acc[2][3]);
            acc[3][0] = fmaf(x3, wv.x, acc[3][0]);
            acc[3][1] = fmaf(x3, wv.y, acc[3][1]);
            acc[3][2] = fmaf(x3, wv.z, acc[3][2]);
            acc[3][3] = fmaf(x3, wv.w, acc[3][3]);
        }
        __syncthreads();
    }
#pragma unroll
    for (int j = 0; j < 4; ++j) {
        int r = r0 + ty * 4 + j;
        if (r < n) {
            float dv = dinv[r];
            float4 o;
            o.x = acc[j][0] * dv;
            o.y = acc[j][1] * dv;
            o.z = acc[j][2] * dv;
            o.w = acc[j][3] * dv;
            *(float4*)(G + (size_t)r * 64 + tx * 4) = o;
        }
    }
}

// wave per node: coalesced 256B gathers of g[src], register accumulate.
template <bool RELU>
__global__ __launch_bounds__(256) void k_agg(const float* __restrict__ G,
                                             const int* __restrict__ rowp,
                                             const int* __restrict__ esrc,
                                             const float* __restrict__ dinv,
                                             const float* __restrict__ bias,
                                             float* __restrict__ OUT, int n) {
    int lane = threadIdx.x & 63;
    int i = blockIdx.x * (blockDim.x >> 6) + (threadIdx.x >> 6);
    if (i >= n) return;
    float acc = G[(size_t)i * 64 + lane];              // self loop
    int e = rowp[i], e1 = rowp[i + 1];
    for (; e + 8 <= e1; e += 8) {
        int s0 = esrc[e], s1 = esrc[e + 1], s2 = esrc[e + 2], s3 = esrc[e + 3];
        int s4 = esrc[e + 4], s5 = esrc[e + 5], s6 = esrc[e + 6], s7 = esrc[e + 7];
        float a0 = G[(size_t)s0 * 64 + lane];
        float a1 = G[(size_t)s1 * 64 + lane];
        float a2 = G[(size_t)s2 * 64 + lane];
        float a3 = G[(size_t)s3 * 64 + lane];
        float a4 = G[(size_t)s4 * 64 + lane];
        float a5 = G[(size_t)s5 * 64 + lane];
        float a6 = G[(size_t)s6 * 64 + lane];
        float a7 = G[(size_t)s7 * 64 + lane];
        acc += a0 + a1 + a2 + a3 + a4 + a5 + a6 + a7;
    }
    for (; e < e1; ++e) acc += G[(size_t)esrc[e] * 64 + lane];
    float r = dinv[i] * acc + bias[lane];
    if (RELU) r = fmaxf(r, 0.f);
    OUT[(size_t)i * 64 + lane] = r;
}

extern "C" void kernel_launch(void* const* d_in, const int* in_sizes, int n_in,
                              void* d_out, int out_size, void* d_ws, size_t ws_size,
                              hipStream_t stream) {
    const float* x = (const float*)d_in[0];
    const int* ei = (const int*)d_in[1];
    const float* W1 = (const float*)d_in[2];
    const float* b1 = (const float*)d_in[3];
    const float* W2 = (const float*)d_in[4];
    const float* b2 = (const float*)d_in[5];
    float* out = (float*)d_out;

    const int N = in_sizes[0] / 128;
    const long long E = in_sizes[1] / 2;
    const int G_SCAN = (N + 255) / 256;   // <= 512 for N <= 131072

    char* p = (char*)d_ws;
    size_t off = 0;
    auto take = [&](size_t bytes) -> void* {
        void* r = p + off;
        off += (bytes + 255) & ~(size_t)255;
        return r;
    };
    int* cnt = (int*)take((size_t)N * 4);
    int* cursor = (int*)take((size_t)N * 4);
    int* rowp = (int*)take((size_t)(N + 1) * 4);
    int* bsum = (int*)take(512 * 4);
    int* boff = (int*)take(512 * 4);
    int* flag = (int*)take(4);
    float* dinv = (float*)take((size_t)N * 4);
    int* esrc = (int*)take((size_t)E * 4);
    float* gbuf = (float*)take((size_t)N * 64 * 4);
    float* hbuf = (float*)take((size_t)N * 64 * 4);
    (void)ws_size; (void)n_in; (void)out_size;

    int nb_n = (N + 255) / 256;
    int nb_e = (int)((E + 255) / 256);

    k_init<<<nb_n, 256, 0, stream>>>(cnt, cursor, flag, N);
    k_detect<<<4, 256, 0, stream>>>(ei, flag, E);
    k_count<<<nb_e, 256, 0, stream>>>(ei, flag, cnt, E);
    k_scan1<<<G_SCAN, 256, 0, stream>>>(cnt, bsum, N);
    k_scan2<<<1, 512, 0, stream>>>(bsum, boff, G_SCAN);
    k_scan3<<<G_SCAN, 256, 0, stream>>>(cnt, boff, rowp, N);
    k_dinv<<<nb_n, 256, 0, stream>>>(cnt, dinv, N);
    k_scatter<<<nb_e, 256, 0, stream>>>(ei, flag, rowp, cursor, esrc, E);

    k_gemm2<128><<<(N + 63) / 64, 256, 0, stream>>>(x, W1, dinv, gbuf, N);
    k_agg<true><<<(N + 3) / 4, 256, 0, stream>>>(gbuf, rowp, esrc, dinv, b1, hbuf, N);
    k_gemm2<64><<<(N + 63) / 64, 256, 0, stream>>>(hbuf, W2, dinv, gbuf, N);
    k_agg<false><<<(N + 3) / 4, 256, 0, stream>>>(gbuf, rowp, esrc, dinv, b2, out, N);
}